// Round 18
// baseline (1090.500 us; speedup 1.0000x reference)
//
#include <hip/hip_runtime.h>

using i32x4 = __attribute__((ext_vector_type(4))) int;

#define DEVI static __device__ __forceinline__

DEVI void gload_lds16(const void* g, void* l) {
  __builtin_amdgcn_global_load_lds(
      (const __attribute__((address_space(1))) void*)g,
      (__attribute__((address_space(3))) void*)l, 16, 0, 0);
}

template <int N> DEVI void vmcnt_n() {
  asm volatile("s_waitcnt vmcnt(%0)" ::"n"(N) : "memory");
}
template <int N> DEVI void lgkm_n() {
  asm volatile("s_waitcnt lgkmcnt(%0)" ::"n"(N) : "memory");
}

#define FENCE() asm volatile("" ::: "memory")
#define BARX()                    \
  do {                            \
    FENCE();                      \
    __builtin_amdgcn_s_barrier(); \
    FENCE();                      \
  } while (0)
#define SCHB() __builtin_amdgcn_sched_barrier(0)
#define PRIO1() __builtin_amdgcn_s_setprio(1)
#define PRIO0() __builtin_amdgcn_s_setprio(0)

DEVI int pack4(int4 v) {
  return (v.x & 255) | ((v.y & 255) << 8) | ((v.z & 255) << 16) | (v.w << 24);
}

// ---- pre-pass: quantize x only (W pack is folded into the GEMMs) ----
DEVI int quant4(float4 v, float s) {
  float q;
  int r;
  q = fminf(fmaxf(rintf(__fmul_rn(v.x, s)), -127.0f), 127.0f);
  r = (int)q & 255;
  q = fminf(fmaxf(rintf(__fmul_rn(v.y, s)), -127.0f), 127.0f);
  r |= ((int)q & 255) << 8;
  q = fminf(fmaxf(rintf(__fmul_rn(v.z, s)), -127.0f), 127.0f);
  r |= ((int)q & 255) << 16;
  q = fminf(fmaxf(rintf(__fmul_rn(v.w, s)), -127.0f), 127.0f);
  r |= ((int)q & 255) << 24;
  return r;
}

__global__ void __launch_bounds__(256) quantx_kernel(
    const float* __restrict__ x, const float* __restrict__ amax,
    signed char* __restrict__ xq, int nx) {
  const float s = 127.0f / amax[0];
  const float4* __restrict__ src = (const float4*)x;
  int* __restrict__ dst = (int*)xq;
  const int T = gridDim.x * 256;
  int i = blockIdx.x * 256 + threadIdx.x;
  for (; i + 3 * T < nx; i += 4 * T) {
    float4 a = src[i];
    float4 b = src[i + T];
    float4 c = src[i + 2 * T];
    float4 d = src[i + 3 * T];
    dst[i] = quant4(a, s);
    dst[i + T] = quant4(b, s);
    dst[i + 2 * T] = quant4(c, s);
    dst[i + 3 * T] = quant4(d, s);
  }
  for (; i < nx; i += T) dst[i] = quant4(src[i], s);
}

// ---- int8 GEMM (R9 schedule) with B pack-on-stage from raw int32 W ----
// A: [M,K] i8 row-major (gload_lds DMA, unchanged). W: [N,K] int32 — each
// thread loads its 64B int32 slice (4 x int4, issued at tile FRONT), packs
// to 16B i8 at tile END (after the single vmcnt(0)), ds_write_b128 to the
// SAME swizzled LDS address gload_lds used before; lgkm(0) before barrier.
// Mid-tile lgkm ledger counts only ds_reads (writes retired pre-barrier).
// BM=256, BK=128 i8-k, 8 waves (2M x 4N), ONE barrier/tile.

#define STG_A(b, kt)                                                             \
  do {                                                                           \
    const int k0_ = (kt)*128 + scol;                                             \
    gload_lds16(Ab + (size_t)(srow) * K + k0_, &lds[b][tid * 16]);               \
    gload_lds16(Ab + (size_t)(64 + srow) * K + k0_, &lds[b][8192 + tid * 16]);   \
    gload_lds16(Ab + (size_t)(128 + srow) * K + k0_, &lds[b][16384 + tid * 16]); \
    gload_lds16(Ab + (size_t)(192 + srow) * K + k0_, &lds[b][24576 + tid * 16]); \
  } while (0)

#define LD_B(kt)                                                            \
  do {                                                                      \
    const size_t kw_ = (size_t)(kt)*128 + scol;                             \
    _Pragma("unroll") for (int j = 0; j < NN; ++j) {                        \
      const int4* p_ = (const int4*)&Wb[(size_t)(j * 64 + srow) * K + kw_]; \
      bst[j][0] = p_[0];                                                    \
      bst[j][1] = p_[1];                                                    \
      bst[j][2] = p_[2];                                                    \
      bst[j][3] = p_[3];                                                    \
    }                                                                       \
  } while (0)

#define PACKW(b)                                                   \
  do {                                                             \
    _Pragma("unroll") for (int j = 0; j < NN; ++j) {               \
      int4 pw_;                                                    \
      pw_.x = pack4(bst[j][0]);                                    \
      pw_.y = pack4(bst[j][1]);                                    \
      pw_.z = pack4(bst[j][2]);                                    \
      pw_.w = pack4(bst[j][3]);                                    \
      *(int4*)&lds[b][ABYTES + j * 8192 + tid * 16] = pw_;         \
    }                                                              \
  } while (0)

#define AF_(b, m, h) \
  (*(const i32x4*)&lds[b][(wrl + (m)*16 + ro) * 128 + ((h) ? cS1 : cS0)])
#define BF_(b, n, h) \
  (*(const i32x4*)&lds[b][ABYTES + (wcl + (n)*16 + ro) * 128 + ((h) ? cS1 : cS0)])

#define RD_AF(dst, b, m0)            \
  do {                               \
    dst[0][0] = AF_(b, m0, 0);       \
    dst[0][1] = AF_(b, m0, 1);       \
    dst[1][0] = AF_(b, (m0) + 1, 0); \
    dst[1][1] = AF_(b, (m0) + 1, 1); \
  } while (0)

#define READ_BF(b)                                   \
  do {                                               \
    _Pragma("unroll") for (int n = 0; n < NN; ++n) { \
      bf[n][0] = BF_(b, n, 0);                       \
      bf[n][1] = BF_(b, n, 1);                       \
    }                                                \
  } while (0)

#define MFMA_P(mp, af)                                                                     \
  do {                                                                                     \
    _Pragma("unroll") for (int n = 0; n < NN; ++n) {                                       \
      acc[2 * (mp)][n] =                                                                   \
          __builtin_amdgcn_mfma_i32_16x16x64_i8(af[0][0], bf[n][0], acc[2 * (mp)][n], 0, 0, 0); \
      acc[2 * (mp)][n] =                                                                   \
          __builtin_amdgcn_mfma_i32_16x16x64_i8(af[0][1], bf[n][1], acc[2 * (mp)][n], 0, 0, 0); \
      acc[2 * (mp) + 1][n] = __builtin_amdgcn_mfma_i32_16x16x64_i8(                        \
          af[1][0], bf[n][0], acc[2 * (mp) + 1][n], 0, 0, 0);                              \
      acc[2 * (mp) + 1][n] = __builtin_amdgcn_mfma_i32_16x16x64_i8(                        \
          af[1][1], bf[n][1], acc[2 * (mp) + 1][n], 0, 0, 0);                              \
    }                                                                                      \
  } while (0)

// lgkm ledger unchanged (own-wave ds_reads only; ds_writes retired before
// each barrier). vmcnt(0) at tile end retires A-DMA + B int32 loads (both
// issued at tile FRONT -> ~full-tile cover; no counted vmcnt anywhere).
#define TILE_1B(b, t)                              \
  do {                                             \
    RD_AF(afX, b, 0);                              \
    READ_BF(b);                                    \
    RD_AF(afY, b, 2);                              \
    if ((t) + 1 < nt) {                            \
      STG_A(1 - (b), (t) + 1);                     \
      LD_B((t) + 1);                               \
    }                                              \
    lgkm_n<4>(); SCHB();                           \
    PRIO1(); MFMA_P(0, afX); PRIO0();              \
    RD_AF(afX, b, 4);                              \
    lgkm_n<4>(); SCHB();                           \
    PRIO1(); MFMA_P(1, afY); PRIO0();              \
    RD_AF(afY, b, 6);                              \
    lgkm_n<4>(); SCHB();                           \
    PRIO1(); MFMA_P(2, afX); PRIO0();              \
    lgkm_n<0>(); SCHB();                           \
    PRIO1(); MFMA_P(3, afY); PRIO0();              \
    vmcnt_n<0>();                                  \
    if ((t) + 1 < nt) {                            \
      PACKW(1 - (b));                              \
      lgkm_n<0>();                                 \
    }                                              \
  } while (0)

template <int BN, int OUT_I8>
__global__ __launch_bounds__(512, 2) void gemm_r18_kernel(
    const signed char* __restrict__ A, const int* __restrict__ W,
    const int* __restrict__ bias, void* __restrict__ out, int M, int N, int K,
    const float* __restrict__ p_ain, const float* __restrict__ p_aw,
    const float* __restrict__ p_ab, const float* __restrict__ p_anext) {
  static_assert(BN == 256 || BN == 128, "");
  constexpr int NN = BN / 64;
  constexpr int ABYTES = 256 * 128;  // 32 KiB A-tile
  __shared__ signed char lds[2][ABYTES + BN * 128];

  const int tid = threadIdx.x;
  const int lane = tid & 63;
  const int wave = tid >> 6;
  const int wrl = (wave >> 2) * 128;      // wave row offset in 256
  const int wcl = (wave & 3) * (BN / 4);  // wave col offset in BN

  // bijective XCD-chunked swizzle (nwg multiple of 8)
  const int lin = blockIdx.y * gridDim.x + blockIdx.x;
  const int cpx = (gridDim.x * gridDim.y) >> 3;
  const int swz = (lin & 7) * cpx + (lin >> 3);
  const int tileM = (swz / gridDim.x) * 256;
  const int tileN = (swz % gridDim.x) * BN;

  const signed char* Ab = A + (size_t)tileM * K;
  const int* Wb = W + (size_t)tileN * K;  // int32 elements, 1 elem -> 1 i8

  const int srow = tid >> 3;                       // staging row 0..63
  const int scol = ((tid & 7) ^ (srow & 7)) * 16;  // inverse-swizzled src col

  const int ro = lane & 15;  // fragment row within 16
  const int kg = lane >> 4;  // 16B k-group 0..3
  const int cS0 = ((kg ^ (ro & 7)) << 4);        // swizzled slot, k-half 0
  const int cS1 = (((4 + kg) ^ (ro & 7)) << 4);  // swizzled slot, k-half 1

  const int nt = K >> 7;  // K-tiles of 128 (even for all layers)

  i32x4 acc[8][NN] = {};
  i32x4 afX[2][2], afY[2][2], bf[NN][2];
  int4 bst[NN][4];  // B int32 staging regs (64B/thread)

  // prologue: A-DMA(0) + B-loads(0); exact drain; pack into buf0; publish
  STG_A(0, 0);
  LD_B(0);
  vmcnt_n<0>();
  PACKW(0);
  lgkm_n<0>();

  for (int t = 0; t < nt; t += 2) {
    BARX();
    TILE_1B(0, t);
    BARX();
    TILE_1B(1, t + 1);
  }

  // ---- epilogue: dequant + bias (+ relu + requant) ----
  const float s1 = __fmul_rn(p_aw[0], p_ain[0]) / 16129.0f;  // a_w*a_in/127^2
  const float s2 = p_ab[0] / 127.0f;                         // a_b/127
  float qs = 0.0f;
  if (OUT_I8) qs = 127.0f / p_anext[0];

#pragma unroll
  for (int m = 0; m < 8; ++m) {
#pragma unroll
    for (int n = 0; n < NN; ++n) {
      const int col = tileN + wcl + n * 16 + ro;
      const int row0 = tileM + wrl + m * 16 + kg * 4;
      const float bv = __fmul_rn((float)bias[col], s2);
#pragma unroll
      for (int i = 0; i < 4; ++i) {
        float y = __fadd_rn(__fmul_rn((float)acc[m][n][i], s1), bv);
        if (OUT_I8) {
          float rl = fmaxf(y, 0.0f);
          float q = fminf(rintf(__fmul_rn(rl, qs)), 127.0f);
          ((signed char*)out)[(size_t)(row0 + i) * N + col] = (signed char)(int)q;
        } else {
          ((float*)out)[(size_t)(row0 + i) * N + col] = y;
        }
      }
    }
  }
}

extern "C" void kernel_launch(void* const* d_in, const int* in_sizes, int n_in,
                              void* d_out, int out_size, void* d_ws, size_t ws_size,
                              hipStream_t stream) {
  const float* x = (const float*)d_in[0];
  const int* W0 = (const int*)d_in[1];
  const int* b0 = (const int*)d_in[2];
  const int* W2 = (const int*)d_in[3];
  const int* b2 = (const int*)d_in[4];
  const int* W4 = (const int*)d_in[5];
  const int* b4 = (const int*)d_in[6];
  const float* a0_in = (const float*)d_in[7];
  const float* a0_w = (const float*)d_in[8];
  const float* a0_b = (const float*)d_in[9];
  const float* a2_in = (const float*)d_in[10];
  const float* a2_w = (const float*)d_in[11];
  const float* a2_b = (const float*)d_in[12];
  const float* a4_in = (const float*)d_in[13];
  const float* a4_w = (const float*)d_in[14];
  const float* a4_b = (const float*)d_in[15];

  constexpr int Bb = 4096, DIN = 2048, H = 4096, DOUT = 2048;
  constexpr size_t MB = 1u << 20;

  char* ws = (char*)d_ws;
  signed char* xq0 = (signed char*)(ws);            //  8 MB  [0,8)
  signed char* xq1 = (signed char*)(ws + 8 * MB);   // 16 MB  [8,24)
  signed char* xq2 = (signed char*)(ws + 24 * MB);  // 16 MB  [24,40)

  // pre-pass: x quantization only (~40 MB traffic)
  quantx_kernel<<<512, 256, 0, stream>>>(x, a0_in, xq0, Bb * DIN / 4);

  gemm_r18_kernel<256, 1><<<dim3(H / 256, Bb / 256), 512, 0, stream>>>(
      xq0, W0, b0, xq1, Bb, H, DIN, a0_in, a0_w, a0_b, a2_in);
  gemm_r18_kernel<256, 1><<<dim3(H / 256, Bb / 256), 512, 0, stream>>>(
      xq1, W2, b2, xq2, Bb, H, H, a2_in, a2_w, a2_b, a4_in);
  gemm_r18_kernel<128, 0><<<dim3(DOUT / 128, Bb / 256), 512, 0, stream>>>(
      xq2, W4, b4, d_out, Bb, DOUT, H, a4_in, a4_w, a4_b, a4_in);
}

// Round 19
// 173.449 us; speedup vs baseline: 6.2872x; 6.2872x over previous
//
#include <hip/hip_runtime.h>

using i32x4 = __attribute__((ext_vector_type(4))) int;

#define DEVI static __device__ __forceinline__

DEVI void gload_lds16(const void* g, void* l) {
  __builtin_amdgcn_global_load_lds(
      (const __attribute__((address_space(1))) void*)g,
      (__attribute__((address_space(3))) void*)l, 16, 0, 0);
}

template <int N> DEVI void vmcnt_n() {
  asm volatile("s_waitcnt vmcnt(%0)" ::"n"(N) : "memory");
}
template <int N> DEVI void lgkm_n() {
  asm volatile("s_waitcnt lgkmcnt(%0)" ::"n"(N) : "memory");
}

#define FENCE() asm volatile("" ::: "memory")
#define BARX()                    \
  do {                            \
    FENCE();                      \
    __builtin_amdgcn_s_barrier(); \
    FENCE();                      \
  } while (0)
#define SCHB() __builtin_amdgcn_sched_barrier(0)
#define PRIO1() __builtin_amdgcn_s_setprio(1)
#define PRIO0() __builtin_amdgcn_s_setprio(0)

DEVI int pack4(int4 v) {
  return (v.x & 255) | ((v.y & 255) << 8) | ((v.z & 255) << 16) | (v.w << 24);
}

DEVI int quant4(float4 v, float s) {
  float q;
  int r;
  q = fminf(fmaxf(rintf(__fmul_rn(v.x, s)), -127.0f), 127.0f);
  r = (int)q & 255;
  q = fminf(fmaxf(rintf(__fmul_rn(v.y, s)), -127.0f), 127.0f);
  r |= ((int)q & 255) << 8;
  q = fminf(fmaxf(rintf(__fmul_rn(v.z, s)), -127.0f), 127.0f);
  r |= ((int)q & 255) << 16;
  q = fminf(fmaxf(rintf(__fmul_rn(v.w, s)), -127.0f), 127.0f);
  r |= ((int)q & 255) << 24;
  return r;
}

// ---- pre-pass: W0 pack + x quant only (W2/W4 packed inside the GEMMs) ----
__global__ void __launch_bounds__(256) prep_kernel(
    const int* __restrict__ W0, const float* __restrict__ x,
    const float* __restrict__ amax, signed char* __restrict__ W0q,
    signed char* __restrict__ xq, int n0, int nx, int s0, int sx) {
  const int bid = blockIdx.x;
  const int tid = threadIdx.x;
  if (bid < s0) {
    const int4* __restrict__ src = (const int4*)W0;
    int* __restrict__ dst = (int*)W0q;
    const int T = s0 * 256;
    int i = bid * 256 + tid;
    for (; i + 3 * T < n0; i += 4 * T) {
      int4 a = src[i];
      int4 b = src[i + T];
      int4 c = src[i + 2 * T];
      int4 d = src[i + 3 * T];
      dst[i] = pack4(a);
      dst[i + T] = pack4(b);
      dst[i + 2 * T] = pack4(c);
      dst[i + 3 * T] = pack4(d);
    }
    for (; i < n0; i += T) dst[i] = pack4(src[i]);
  } else {
    const float s = 127.0f / amax[0];
    const int lb = bid - s0;
    const float4* __restrict__ src = (const float4*)x;
    int* __restrict__ dst = (int*)xq;
    const int T = sx * 256;
    int i = lb * 256 + tid;
    for (; i + 3 * T < nx; i += 4 * T) {
      float4 a = src[i];
      float4 b = src[i + T];
      float4 c = src[i + 2 * T];
      float4 d = src[i + 3 * T];
      dst[i] = quant4(a, s);
      dst[i + T] = quant4(b, s);
      dst[i + 2 * T] = quant4(c, s);
      dst[i + 3 * T] = quant4(d, s);
    }
    for (; i < nx; i += T) dst[i] = quant4(src[i], s);
  }
}

// ---- int8 GEMM (R9/R14 structure, verbatim) + interleaved next-layer W
// ---- pack: per 2-tile iteration, each thread loads CPI x 16B of int32 W
// ---- (issued at iteration FRONT -> full-tile vmcnt(0) cover), packs and
// ---- stores it the NEXT iteration. Chunk map: chunk g covers int32
// ---- elements [g*2048, (g+1)*2048) -> i8 bytes, identity re-layout.
// BM=256, BK=128 bytes, 8 waves (2M x 4N).

#define STG(b, kt)                                                               \
  do {                                                                           \
    const int k0_ = (kt)*128 + scol;                                             \
    _Pragma("unroll") for (int j = 0; j < NN; ++j)                               \
        gload_lds16(Wb + (size_t)((j)*64 + srow) * K + k0_,                      \
                    &lds[b][ABYTES + (j)*8192 + tid * 16]);                      \
    gload_lds16(Ab + (size_t)(srow) * K + k0_, &lds[b][tid * 16]);               \
    gload_lds16(Ab + (size_t)(64 + srow) * K + k0_, &lds[b][8192 + tid * 16]);   \
    gload_lds16(Ab + (size_t)(128 + srow) * K + k0_, &lds[b][16384 + tid * 16]); \
    gload_lds16(Ab + (size_t)(192 + srow) * K + k0_, &lds[b][24576 + tid * 16]); \
  } while (0)

#define AF_(b, m, h) \
  (*(const i32x4*)&lds[b][(wrl + (m)*16 + ro) * 128 + ((h) ? cS1 : cS0)])
#define BF_(b, n, h) \
  (*(const i32x4*)&lds[b][ABYTES + (wcl + (n)*16 + ro) * 128 + ((h) ? cS1 : cS0)])

#define RD_AF(dst, b, m0)            \
  do {                               \
    dst[0][0] = AF_(b, m0, 0);       \
    dst[0][1] = AF_(b, m0, 1);       \
    dst[1][0] = AF_(b, (m0) + 1, 0); \
    dst[1][1] = AF_(b, (m0) + 1, 1); \
  } while (0)

#define READ_BF(b)                                   \
  do {                                               \
    _Pragma("unroll") for (int n = 0; n < NN; ++n) { \
      bf[n][0] = BF_(b, n, 0);                       \
      bf[n][1] = BF_(b, n, 1);                       \
    }                                                \
  } while (0)

#define MFMA_P(mp, af)                                                                     \
  do {                                                                                     \
    _Pragma("unroll") for (int n = 0; n < NN; ++n) {                                       \
      acc[2 * (mp)][n] =                                                                   \
          __builtin_amdgcn_mfma_i32_16x16x64_i8(af[0][0], bf[n][0], acc[2 * (mp)][n], 0, 0, 0); \
      acc[2 * (mp)][n] =                                                                   \
          __builtin_amdgcn_mfma_i32_16x16x64_i8(af[0][1], bf[n][1], acc[2 * (mp)][n], 0, 0, 0); \
      acc[2 * (mp) + 1][n] = __builtin_amdgcn_mfma_i32_16x16x64_i8(                        \
          af[1][0], bf[n][0], acc[2 * (mp) + 1][n], 0, 0, 0);                              \
      acc[2 * (mp) + 1][n] = __builtin_amdgcn_mfma_i32_16x16x64_i8(                        \
          af[1][1], bf[n][1], acc[2 * (mp) + 1][n], 0, 0, 0);                              \
    }                                                                                      \
  } while (0)

// lgkm ledger (own-wave ds_reads only), unchanged from R9/R14.
#define TILE_1B(b, t)                              \
  do {                                             \
    RD_AF(afX, b, 0);                              \
    READ_BF(b);                                    \
    RD_AF(afY, b, 2);                              \
    if ((t) + 1 < nt) STG(1 - (b), (t) + 1);       \
    lgkm_n<4>(); SCHB();                           \
    PRIO1(); MFMA_P(0, afX); PRIO0();              \
    RD_AF(afX, b, 4);                              \
    lgkm_n<4>(); SCHB();                           \
    PRIO1(); MFMA_P(1, afY); PRIO0();              \
    RD_AF(afY, b, 6);                              \
    lgkm_n<4>(); SCHB();                           \
    PRIO1(); MFMA_P(2, afX); PRIO0();              \
    lgkm_n<0>(); SCHB();                           \
    PRIO1(); MFMA_P(3, afY); PRIO0();              \
    vmcnt_n<0>();                                  \
  } while (0)

template <int BN, int CPI, int OUT_I8>
__global__ __launch_bounds__(512, 2) void gemm_r19_kernel(
    const signed char* __restrict__ A, const signed char* __restrict__ W,
    const int* __restrict__ bias, void* __restrict__ out, int M, int N, int K,
    const float* __restrict__ p_ain, const float* __restrict__ p_aw,
    const float* __restrict__ p_ab, const float* __restrict__ p_anext,
    const int* __restrict__ pw, signed char* __restrict__ po) {
  static_assert(BN == 256 || BN == 128, "");
  constexpr int NN = BN / 64;
  constexpr int ABYTES = 256 * 128;  // 32 KiB A-tile
  __shared__ signed char lds[2][ABYTES + BN * 128];

  const int tid = threadIdx.x;
  const int lane = tid & 63;
  const int wave = tid >> 6;
  const int wrl = (wave >> 2) * 128;      // wave row offset in 256
  const int wcl = (wave & 3) * (BN / 4);  // wave col offset in BN

  // bijective XCD-chunked swizzle (nwg multiple of 8)
  const int lin = blockIdx.y * gridDim.x + blockIdx.x;
  const int cpx = (gridDim.x * gridDim.y) >> 3;
  const int swz = (lin & 7) * cpx + (lin >> 3);
  const int tileM = (swz / gridDim.x) * 256;
  const int tileN = (swz % gridDim.x) * BN;

  const signed char* Ab = A + (size_t)tileM * K;
  const signed char* Wb = W + (size_t)tileN * K;

  const int srow = tid >> 3;                       // staging row 0..63
  const int scol = ((tid & 7) ^ (srow & 7)) * 16;  // inverse-swizzled src col

  const int ro = lane & 15;  // fragment row within 16
  const int kg = lane >> 4;  // 16B k-group 0..3
  const int cS0 = ((kg ^ (ro & 7)) << 4);        // swizzled slot, k-half 0
  const int cS1 = (((4 + kg) ^ (ro & 7)) << 4);  // swizzled slot, k-half 1

  const int nt = K >> 7;  // K-tiles of 128 bytes

  i32x4 acc[8][NN] = {};
  i32x4 afX[2][2], afY[2][2], bf[NN][2];
  int4 wpk[CPI > 0 ? CPI : 1];
  const size_t chunkbase = (size_t)lin * (CPI > 0 ? CPI * (nt >> 1) : 0);

  // prologue: stage tile 0, retire own issues; loop-entry barrier publishes
  STG(0, 0);
  vmcnt_n<0>();

  for (int t = 0; t < nt; t += 2) {
    if constexpr (CPI > 0) {
      const int it = t >> 1;
      if (it > 0) {
#pragma unroll
        for (int c = 0; c < CPI; ++c)
          ((int*)po)[(chunkbase + (size_t)(it - 1) * CPI + c) * 512 + tid] =
              pack4(wpk[c]);
      }
#pragma unroll
      for (int c = 0; c < CPI; ++c)
        wpk[c] =
            *((const int4*)(pw + (chunkbase + (size_t)it * CPI + c) * 2048) +
              tid);
    }
    BARX();
    TILE_1B(0, t);
    BARX();
    TILE_1B(1, t + 1);
  }
  if constexpr (CPI > 0) {
    const int itl = (nt >> 1) - 1;
#pragma unroll
    for (int c = 0; c < CPI; ++c)
      ((int*)po)[(chunkbase + (size_t)itl * CPI + c) * 512 + tid] =
          pack4(wpk[c]);
  }

  // ---- epilogue: dequant + bias (+ relu + requant) ----
  const float s1 = __fmul_rn(p_aw[0], p_ain[0]) / 16129.0f;  // a_w*a_in/127^2
  const float s2 = p_ab[0] / 127.0f;                         // a_b/127
  float qs = 0.0f;
  if (OUT_I8) qs = 127.0f / p_anext[0];

#pragma unroll
  for (int m = 0; m < 8; ++m) {
#pragma unroll
    for (int n = 0; n < NN; ++n) {
      const int col = tileN + wcl + n * 16 + ro;
      const int row0 = tileM + wrl + m * 16 + kg * 4;
      const float bv = __fmul_rn((float)bias[col], s2);
#pragma unroll
      for (int i = 0; i < 4; ++i) {
        float y = __fadd_rn(__fmul_rn((float)acc[m][n][i], s1), bv);
        if (OUT_I8) {
          float rl = fmaxf(y, 0.0f);
          float q = fminf(rintf(__fmul_rn(rl, qs)), 127.0f);
          ((signed char*)out)[(size_t)(row0 + i) * N + col] = (signed char)(int)q;
        } else {
          ((float*)out)[(size_t)(row0 + i) * N + col] = y;
        }
      }
    }
  }
}

extern "C" void kernel_launch(void* const* d_in, const int* in_sizes, int n_in,
                              void* d_out, int out_size, void* d_ws, size_t ws_size,
                              hipStream_t stream) {
  const float* x = (const float*)d_in[0];
  const int* W0 = (const int*)d_in[1];
  const int* b0 = (const int*)d_in[2];
  const int* W2 = (const int*)d_in[3];
  const int* b2 = (const int*)d_in[4];
  const int* W4 = (const int*)d_in[5];
  const int* b4 = (const int*)d_in[6];
  const float* a0_in = (const float*)d_in[7];
  const float* a0_w = (const float*)d_in[8];
  const float* a0_b = (const float*)d_in[9];
  const float* a2_in = (const float*)d_in[10];
  const float* a2_w = (const float*)d_in[11];
  const float* a2_b = (const float*)d_in[12];
  const float* a4_in = (const float*)d_in[13];
  const float* a4_w = (const float*)d_in[14];
  const float* a4_b = (const float*)d_in[15];

  constexpr int Bb = 4096, DIN = 2048, H = 4096, DOUT = 2048;
  constexpr size_t MB = 1u << 20;

  char* ws = (char*)d_ws;
  signed char* xq0 = (signed char*)(ws);           //  8 MB  [0,8)
  signed char* xq2 = (signed char*)(ws);           // 16 MB  [0,16) (aliases xq0+W0q, dead then)
  signed char* W0q = (signed char*)(ws + 8 * MB);  //  8 MB  [8,16)
  signed char* W2q = (signed char*)(ws + 16 * MB); // 16 MB  [16,32)
  signed char* W4q = (signed char*)(ws + 32 * MB); //  8 MB  [32,40)
  signed char* xq1 = (signed char*)(ws + 40 * MB); // 16 MB  [40,56)

  // pre-pass: W0 pack + x quant only (~80 MB)
  const int n0 = H * DIN / 4, nx = Bb * DIN / 4;
  prep_kernel<<<2048, 256, 0, stream>>>(W0, x, a0_in, W0q, xq0, n0, nx, 1024,
                                        1024);

  // GEMM1 packs W2 (4 chunks/iter x 8 iters x 256 blocks = 64 MB);
  // GEMM2 packs W4 (1 chunk/iter x 16 iters x 256 blocks = 32 MB).
  gemm_r19_kernel<256, 4, 1><<<dim3(H / 256, Bb / 256), 512, 0, stream>>>(
      xq0, W0q, b0, xq1, Bb, H, DIN, a0_in, a0_w, a0_b, a2_in, W2, W2q);
  gemm_r19_kernel<256, 1, 1><<<dim3(H / 256, Bb / 256), 512, 0, stream>>>(
      xq1, W2q, b2, xq2, Bb, H, H, a2_in, a2_w, a2_b, a4_in, W4, W4q);
  gemm_r19_kernel<128, 0, 0><<<dim3(DOUT / 128, Bb / 256), 512, 0, stream>>>(
      xq2, W4q, b4, d_out, Bb, DOUT, H, a4_in, a4_w, a4_b, a4_in, nullptr,
      nullptr);
}

// Round 20
// 159.397 us; speedup vs baseline: 6.8414x; 1.0882x over previous
//
#include <hip/hip_runtime.h>

using i32x4 = __attribute__((ext_vector_type(4))) int;

#define DEVI static __device__ __forceinline__

DEVI void gload_lds16(const void* g, void* l) {
  __builtin_amdgcn_global_load_lds(
      (const __attribute__((address_space(1))) void*)g,
      (__attribute__((address_space(3))) void*)l, 16, 0, 0);
}

template <int N> DEVI void vmcnt_n() {
  asm volatile("s_waitcnt vmcnt(%0)" ::"n"(N) : "memory");
}
template <int N> DEVI void lgkm_n() {
  asm volatile("s_waitcnt lgkmcnt(%0)" ::"n"(N) : "memory");
}

#define FENCE() asm volatile("" ::: "memory")
#define BARX()                    \
  do {                            \
    FENCE();                      \
    __builtin_amdgcn_s_barrier(); \
    FENCE();                      \
  } while (0)
#define SCHB() __builtin_amdgcn_sched_barrier(0)
#define PRIO1() __builtin_amdgcn_s_setprio(1)
#define PRIO0() __builtin_amdgcn_s_setprio(0)

// ---- fused pre-pass (single launch): pack W0/W2/W4 int32->int8 + quant x ----
// Measured (R14): ~35 us wall — at the copy roofline for its 200 MB of
// traffic. All attempts to overlap this with the GEMMs regressed
// (R13 tail-fold, R18 in-loop fold, R19 interleave).
__global__ void __launch_bounds__(256) prep_kernel(
    const int* __restrict__ W0, const int* __restrict__ W2,
    const int* __restrict__ W4, const float* __restrict__ x,
    const float* __restrict__ amax, signed char* __restrict__ W0q,
    signed char* __restrict__ W2q, signed char* __restrict__ W4q,
    signed char* __restrict__ xq, int c0, int c2, int c4, int cx) {
  const float s = 127.0f / amax[0];
  const int cw = c0 + c2 + c4;
  const int total = cw + cx;
  int stride = gridDim.x * blockDim.x;
  for (int i = blockIdx.x * blockDim.x + threadIdx.x; i < total; i += stride) {
    if (i < cw) {
      const int* w;
      signed char* o;
      int j = i;
      if (j < c0) {
        w = W0; o = W0q;
      } else if (j < c0 + c2) {
        j -= c0; w = W2; o = W2q;
      } else {
        j -= c0 + c2; w = W4; o = W4q;
      }
      int4 v = reinterpret_cast<const int4*>(w)[j];
      char4 c;
      c.x = (signed char)v.x;
      c.y = (signed char)v.y;
      c.z = (signed char)v.z;
      c.w = (signed char)v.w;
      reinterpret_cast<char4*>(o)[j] = c;
    } else {
      int j = i - cw;
      float4 v = reinterpret_cast<const float4*>(x)[j];
      char4 c;
      float q;
      q = fminf(fmaxf(rintf(__fmul_rn(v.x, s)), -127.0f), 127.0f); c.x = (signed char)(int)q;
      q = fminf(fmaxf(rintf(__fmul_rn(v.y, s)), -127.0f), 127.0f); c.y = (signed char)(int)q;
      q = fminf(fmaxf(rintf(__fmul_rn(v.z, s)), -127.0f), 127.0f); c.z = (signed char)(int)q;
      q = fminf(fmaxf(rintf(__fmul_rn(v.w, s)), -127.0f), 127.0f); c.w = (signed char)(int)q;
      reinterpret_cast<char4*>(xq)[j] = c;
    }
  }
}

// ---- int8 GEMM (measured best, R9/R14 structure): dbuf XOR-swizzled LDS,
// ---- gload_lds width-16 DMA, ONE barrier/tile, own-wave in-order lgkm
// ---- ledger, single vmcnt(0) tile-end drain (full-tile latency cover; no
// ---- counted cross-class vmcnt — R6 lesson). BM=256, BK=128 bytes,
// ---- 8 waves (2M x 4N), per-wave C = 128 x (BN/4).
// Plateau notes: five schedule families land at tile = MFMA + LDS serial
// (GEMM2 61.5 us, MfmaUtil 44%); 32x32 MFMA conflicts (R5); B-streaming
// uncoalesced (R8); double-barrier regresses (R16).

#define STG(b, kt)                                                               \
  do {                                                                           \
    const int k0_ = (kt)*128 + scol;                                             \
    _Pragma("unroll") for (int j = 0; j < NN; ++j)                               \
        gload_lds16(Wb + (size_t)((j)*64 + srow) * K + k0_,                      \
                    &lds[b][ABYTES + (j)*8192 + tid * 16]);                      \
    gload_lds16(Ab + (size_t)(srow) * K + k0_, &lds[b][tid * 16]);               \
    gload_lds16(Ab + (size_t)(64 + srow) * K + k0_, &lds[b][8192 + tid * 16]);   \
    gload_lds16(Ab + (size_t)(128 + srow) * K + k0_, &lds[b][16384 + tid * 16]); \
    gload_lds16(Ab + (size_t)(192 + srow) * K + k0_, &lds[b][24576 + tid * 16]); \
  } while (0)

#define AF_(b, m, h) \
  (*(const i32x4*)&lds[b][(wrl + (m)*16 + ro) * 128 + ((h) ? cS1 : cS0)])
#define BF_(b, n, h) \
  (*(const i32x4*)&lds[b][ABYTES + (wcl + (n)*16 + ro) * 128 + ((h) ? cS1 : cS0)])

#define RD_AF(dst, b, m0)            \
  do {                               \
    dst[0][0] = AF_(b, m0, 0);       \
    dst[0][1] = AF_(b, m0, 1);       \
    dst[1][0] = AF_(b, (m0) + 1, 0); \
    dst[1][1] = AF_(b, (m0) + 1, 1); \
  } while (0)

#define READ_BF(b)                                   \
  do {                                               \
    _Pragma("unroll") for (int n = 0; n < NN; ++n) { \
      bf[n][0] = BF_(b, n, 0);                       \
      bf[n][1] = BF_(b, n, 1);                       \
    }                                                \
  } while (0)

#define MFMA_P(mp, af)                                                                     \
  do {                                                                                     \
    _Pragma("unroll") for (int n = 0; n < NN; ++n) {                                       \
      acc[2 * (mp)][n] =                                                                   \
          __builtin_amdgcn_mfma_i32_16x16x64_i8(af[0][0], bf[n][0], acc[2 * (mp)][n], 0, 0, 0); \
      acc[2 * (mp)][n] =                                                                   \
          __builtin_amdgcn_mfma_i32_16x16x64_i8(af[0][1], bf[n][1], acc[2 * (mp)][n], 0, 0, 0); \
      acc[2 * (mp) + 1][n] = __builtin_amdgcn_mfma_i32_16x16x64_i8(                        \
          af[1][0], bf[n][0], acc[2 * (mp) + 1][n], 0, 0, 0);                              \
      acc[2 * (mp) + 1][n] = __builtin_amdgcn_mfma_i32_16x16x64_i8(                        \
          af[1][1], bf[n][1], acc[2 * (mp) + 1][n], 0, 0, 0);                              \
    }                                                                                      \
  } while (0)

// lgkm ledger (own-wave ds_reads only, in-order retirement):
//  issue afX(4)+BF(8)+afY(4)=16; lgkm(4) retires afX+BF -> MFMA0(afX)
//  issue afX'(4); lgkm(4) retires afY -> MFMA1(afY); issue afY'(4);
//  lgkm(4) retires afX' -> MFMA2; lgkm(0) -> MFMA3.
#define TILE_1B(b, t)                              \
  do {                                             \
    RD_AF(afX, b, 0);                              \
    READ_BF(b);                                    \
    RD_AF(afY, b, 2);                              \
    if ((t) + 1 < nt) STG(1 - (b), (t) + 1);       \
    lgkm_n<4>(); SCHB();                           \
    PRIO1(); MFMA_P(0, afX); PRIO0();              \
    RD_AF(afX, b, 4);                              \
    lgkm_n<4>(); SCHB();                           \
    PRIO1(); MFMA_P(1, afY); PRIO0();              \
    RD_AF(afY, b, 6);                              \
    lgkm_n<4>(); SCHB();                           \
    PRIO1(); MFMA_P(2, afX); PRIO0();              \
    lgkm_n<0>(); SCHB();                           \
    PRIO1(); MFMA_P(3, afY); PRIO0();              \
    vmcnt_n<0>();                                  \
  } while (0)

template <int BN, int OUT_I8>
__global__ __launch_bounds__(512, 2) void gemm_final_kernel(
    const signed char* __restrict__ A, const signed char* __restrict__ W,
    const int* __restrict__ bias, void* __restrict__ out, int M, int N, int K,
    const float* __restrict__ p_ain, const float* __restrict__ p_aw,
    const float* __restrict__ p_ab, const float* __restrict__ p_anext) {
  static_assert(BN == 256 || BN == 128, "");
  constexpr int NN = BN / 64;
  constexpr int ABYTES = 256 * 128;  // 32 KiB A-tile
  __shared__ signed char lds[2][ABYTES + BN * 128];

  const int tid = threadIdx.x;
  const int lane = tid & 63;
  const int wave = tid >> 6;
  const int wrl = (wave >> 2) * 128;      // wave row offset in 256
  const int wcl = (wave & 3) * (BN / 4);  // wave col offset in BN

  // bijective XCD-chunked swizzle (nwg multiple of 8)
  const int lin = blockIdx.y * gridDim.x + blockIdx.x;
  const int cpx = (gridDim.x * gridDim.y) >> 3;
  const int swz = (lin & 7) * cpx + (lin >> 3);
  const int tileM = (swz / gridDim.x) * 256;
  const int tileN = (swz % gridDim.x) * BN;

  const signed char* Ab = A + (size_t)tileM * K;
  const signed char* Wb = W + (size_t)tileN * K;

  const int srow = tid >> 3;                       // staging row 0..63
  const int scol = ((tid & 7) ^ (srow & 7)) * 16;  // inverse-swizzled src col

  const int ro = lane & 15;  // fragment row within 16
  const int kg = lane >> 4;  // 16B k-group 0..3
  const int cS0 = ((kg ^ (ro & 7)) << 4);        // swizzled slot, k-half 0
  const int cS1 = (((4 + kg) ^ (ro & 7)) << 4);  // swizzled slot, k-half 1

  const int nt = K >> 7;  // K-tiles of 128 bytes

  i32x4 acc[8][NN] = {};
  i32x4 afX[2][2], afY[2][2], bf[NN][2];

  // prologue: stage tile 0, retire own issues; loop-entry barrier publishes
  STG(0, 0);
  vmcnt_n<0>();

  for (int t = 0; t < nt; t += 2) {
    BARX();
    TILE_1B(0, t);
    BARX();
    TILE_1B(1, t + 1);
  }

  // ---- epilogue: dequant + bias (+ relu + requant) ----
  const float s1 = __fmul_rn(p_aw[0], p_ain[0]) / 16129.0f;  // a_w*a_in/127^2
  const float s2 = p_ab[0] / 127.0f;                         // a_b/127
  float qs = 0.0f;
  if (OUT_I8) qs = 127.0f / p_anext[0];

#pragma unroll
  for (int m = 0; m < 8; ++m) {
#pragma unroll
    for (int n = 0; n < NN; ++n) {
      const int col = tileN + wcl + n * 16 + ro;
      const int row0 = tileM + wrl + m * 16 + kg * 4;
      const float bv = __fmul_rn((float)bias[col], s2);
#pragma unroll
      for (int i = 0; i < 4; ++i) {
        float y = __fadd_rn(__fmul_rn((float)acc[m][n][i], s1), bv);
        if (OUT_I8) {
          float rl = fmaxf(y, 0.0f);
          float q = fminf(rintf(__fmul_rn(rl, qs)), 127.0f);
          ((signed char*)out)[(size_t)(row0 + i) * N + col] = (signed char)(int)q;
        } else {
          ((float*)out)[(size_t)(row0 + i) * N + col] = y;
        }
      }
    }
  }
}

extern "C" void kernel_launch(void* const* d_in, const int* in_sizes, int n_in,
                              void* d_out, int out_size, void* d_ws, size_t ws_size,
                              hipStream_t stream) {
  const float* x = (const float*)d_in[0];
  const int* W0 = (const int*)d_in[1];
  const int* b0 = (const int*)d_in[2];
  const int* W2 = (const int*)d_in[3];
  const int* b2 = (const int*)d_in[4];
  const int* W4 = (const int*)d_in[5];
  const int* b4 = (const int*)d_in[6];
  const float* a0_in = (const float*)d_in[7];
  const float* a0_w = (const float*)d_in[8];
  const float* a0_b = (const float*)d_in[9];
  const float* a2_in = (const float*)d_in[10];
  const float* a2_w = (const float*)d_in[11];
  const float* a2_b = (const float*)d_in[12];
  const float* a4_in = (const float*)d_in[13];
  const float* a4_w = (const float*)d_in[14];
  const float* a4_b = (const float*)d_in[15];

  constexpr int Bb = 4096, DIN = 2048, H = 4096, DOUT = 2048;
  constexpr size_t MB = 1u << 20;

  char* ws = (char*)d_ws;
  signed char* xq0 = (signed char*)(ws);           //  8 MB  [0,8)
  signed char* xq2 = (signed char*)(ws);           // 16 MB  [0,16) (aliases xq0+W0q, dead then)
  signed char* W0q = (signed char*)(ws + 8 * MB);  //  8 MB  [8,16)
  signed char* W2q = (signed char*)(ws + 16 * MB); // 16 MB  [16,32)
  signed char* W4q = (signed char*)(ws + 32 * MB); //  8 MB  [32,40)
  signed char* xq1 = (signed char*)(ws + 40 * MB); // 16 MB  [40,56)

  // single fused pre-pass launch
  prep_kernel<<<2048, 256, 0, stream>>>(W0, W2, W4, x, a0_in, W0q, W2q, W4q,
                                        xq0, H * DIN / 4, H * H / 4,
                                        DOUT * H / 4, Bb * DIN / 4);

  gemm_final_kernel<256, 1><<<dim3(H / 256, Bb / 256), 512, 0, stream>>>(
      xq0, W0q, b0, xq1, Bb, H, DIN, a0_in, a0_w, a0_b, a2_in);
  gemm_final_kernel<256, 1><<<dim3(H / 256, Bb / 256), 512, 0, stream>>>(
      xq1, W2q, b2, xq2, Bb, H, H, a2_in, a2_w, a2_b, a4_in);
  gemm_final_kernel<128, 0><<<dim3(DOUT / 128, Bb / 256), 512, 0, stream>>>(
      xq2, W4q, b4, d_out, Bb, DOUT, H, a4_in, a4_w, a4_b, a4_in);
}